// Round 5
// baseline (188.044 us; speedup 1.0000x reference)
//
#include <hip/hip_runtime.h>

// RelativeMultiHeadSelfAttention: B=16, S=1024, C=256, H=8 heads, D=32 head_dim
// prep (casts + bias gather *INV_LN2) -> QKV GEMM (bf16 MFMA, q scaled by
// SCALE*INV_LN2, V written transposed [bh][d][s]) -> fused attention
// (BARRIER-FREE: K/V/bias MFMA fragments loaded directly from global — both
// are 16B-contiguous; LDS only for per-wave P round-trip) -> merge GEMM.

typedef __attribute__((ext_vector_type(8))) short bf16x8;
typedef __attribute__((ext_vector_type(4))) float f32x4;

#define INV_LN2 1.44269504088896340736f

__device__ __forceinline__ unsigned short f2bf(float f) {
  union { float f; unsigned u; } v; v.f = f;
  unsigned r = v.u + 0x7fffu + ((v.u >> 16) & 1u);   // RNE
  return (unsigned short)(r >> 16);
}
__device__ __forceinline__ float u2f(unsigned u) {
  union { unsigned u; float f; } v; v.u = u;
  return v.f;
}

// ---------------- prep: casts + bias gather ----------------
__global__ __launch_bounds__(256) void prep_kernel(
    const float* __restrict__ x, const float* __restrict__ wq,
    const float* __restrict__ wm, const float* __restrict__ tab,
    const int* __restrict__ idx,
    unsigned short* __restrict__ xb, unsigned short* __restrict__ wqb,
    unsigned short* __restrict__ wmb, unsigned short* __restrict__ biasb) {
  const long NX = 1048576, NW1 = 49152, NW2 = 16384, NB = 262144;
  long u = (long)blockIdx.x * 256 + threadIdx.x;
  if (u < NX) {
    float4 v = ((const float4*)x)[u];
    ushort4 o; o.x = f2bf(v.x); o.y = f2bf(v.y); o.z = f2bf(v.z); o.w = f2bf(v.w);
    ((ushort4*)xb)[u] = o;
  } else if (u < NX + NW1) {
    long t = u - NX;
    float4 v = ((const float4*)wq)[t];
    ushort4 o; o.x = f2bf(v.x); o.y = f2bf(v.y); o.z = f2bf(v.z); o.w = f2bf(v.w);
    ((ushort4*)wqb)[t] = o;
  } else if (u < NX + NW1 + NW2) {
    long t = u - NX - NW1;
    float4 v = ((const float4*)wm)[t];
    ushort4 o; o.x = f2bf(v.x); o.y = f2bf(v.y); o.z = f2bf(v.z); o.w = f2bf(v.w);
    ((ushort4*)wmb)[t] = o;
  } else if (u < NX + NW1 + NW2 + NB) {
    long t = u - NX - NW1 - NW2;
    int4 iv = ((const int4*)idx)[t];
    ushort4 o;
    o.x = f2bf(tab[(long)iv.x * 8] * INV_LN2);
    o.y = f2bf(tab[(long)iv.y * 8] * INV_LN2);
    o.z = f2bf(tab[(long)iv.z * 8] * INV_LN2);
    o.w = f2bf(tab[(long)iv.w * 8] * INV_LN2);
    ((ushort4*)biasb)[t] = o;
  }
}

// ---------------- GEMM (QKV / merge) ----------------
// C[m,n] = sum_k A[m,k]*Bw[n,k] (+ bias[n]); padded LDS [128][40].
// MODE 0: q/k -> [bh][s][32]; V -> TRANSPOSED [bh][d][1024]. MODE 1: f32 out.
template <int MODE>
__global__ __launch_bounds__(256) void gemm_k(
    const unsigned short* __restrict__ A, const unsigned short* __restrict__ Bw,
    const float* __restrict__ bias,
    unsigned short* __restrict__ q_ws, unsigned short* __restrict__ k_ws,
    unsigned short* __restrict__ v_ws, float* __restrict__ out) {
  __shared__ __align__(16) unsigned short As[128 * 40];
  __shared__ __align__(16) unsigned short Bs[128 * 40];
  const int tid = threadIdx.x;
  const int lane = tid & 63, wid = tid >> 6;
  const int wm = wid >> 1, wn = wid & 1;
  const int li = lane & 15, g = lane >> 4;
  const int m0 = blockIdx.y * 128;
  const int n0 = blockIdx.x * 128;
  f32x4 acc[4][4] = {};
  const int srow = tid >> 2, sg = tid & 3;
  const unsigned short* Ag = A + (long)(m0 + srow) * 256 + sg * 8;
  const unsigned short* Bg = Bw + (long)(n0 + srow) * 256 + sg * 8;

  for (int kt = 0; kt < 8; ++kt) {
    const int k0 = kt * 32;
    bf16x8 a0 = *(const bf16x8*)(Ag + k0);
    bf16x8 a1 = *(const bf16x8*)(Ag + 64 * 256 + k0);
    bf16x8 b0 = *(const bf16x8*)(Bg + k0);
    bf16x8 b1 = *(const bf16x8*)(Bg + 64 * 256 + k0);
    __syncthreads();
    *(bf16x8*)(As + srow * 40 + sg * 8) = a0;
    *(bf16x8*)(As + (srow + 64) * 40 + sg * 8) = a1;
    *(bf16x8*)(Bs + srow * 40 + sg * 8) = b0;
    *(bf16x8*)(Bs + (srow + 64) * 40 + sg * 8) = b1;
    __syncthreads();
    bf16x8 af[4], bfr[4];
#pragma unroll
    for (int mi = 0; mi < 4; mi++)
      af[mi] = *(const bf16x8*)(As + (wm * 64 + mi * 16 + li) * 40 + g * 8);
#pragma unroll
    for (int ni = 0; ni < 4; ni++)
      bfr[ni] = *(const bf16x8*)(Bs + (wn * 64 + ni * 16 + li) * 40 + g * 8);
#pragma unroll
    for (int mi = 0; mi < 4; mi++)
#pragma unroll
      for (int ni = 0; ni < 4; ni++)
        acc[mi][ni] = __builtin_amdgcn_mfma_f32_16x16x32_bf16(af[mi], bfr[ni], acc[mi][ni], 0, 0, 0);
  }

  if (MODE == 0) {
    const int sec = n0 >> 8;  // tile never crosses q/k/v section boundaries
    unsigned short* dst = (sec == 0) ? q_ws : k_ws;
    const float qscale = 0.0625f * INV_LN2;   // SCALE * 1/ln2 folded into q
#pragma unroll
    for (int mi = 0; mi < 4; mi++)
#pragma unroll
      for (int ni = 0; ni < 4; ni++)
#pragma unroll
        for (int i = 0; i < 4; i++) {
          int m = m0 + wm * 64 + mi * 16 + g * 4 + i;
          int n = n0 + wn * 64 + ni * 16 + li;
          float val = acc[mi][ni][i] + bias[n];
          if (sec == 0) val *= qscale;
          int h = (n >> 5) & 7, d = n & 31;
          int b = m >> 10, s = m & 1023;
          if (sec == 2)
            v_ws[(long)(b * 8 + h) * 32768 + (long)d * 1024 + s] = f2bf(val);
          else
            dst[((long)(b * 8 + h) * 1024 + s) * 32 + d] = f2bf(val);
        }
  } else {
#pragma unroll
    for (int mi = 0; mi < 4; mi++)
#pragma unroll
      for (int ni = 0; ni < 4; ni++)
#pragma unroll
        for (int i = 0; i < 4; i++) {
          int m = m0 + wm * 64 + mi * 16 + g * 4 + i;
          int n = n0 + wn * 64 + ni * 16 + li;
          out[(long)m * 256 + n] = acc[mi][ni][i] + bias[n];
        }
  }
}

// ---------------- fused attention (barrier-free, direct-global operands) ----
// grid (16 q-tiles, 128 bh); 4 independent waves/WG, each owns 16 q rows.
// sc = mfma(A=K, B=Q, C=bias_l2): lane (li,g) reg i = P_pre[tok=16c+4g+i][q=li].
// kf A-frag = K[tok][d] rows (16B contiguous); vf B-frag = Vt[d][tok] rows
// (16B contiguous) -> no LDS staging, no __syncthreads anywhere.
__global__ __launch_bounds__(256) void attn_kernel(
    const unsigned short* __restrict__ q_ws, const unsigned short* __restrict__ k_ws,
    const unsigned short* __restrict__ vt_ws, const unsigned short* __restrict__ biasb,
    unsigned short* __restrict__ attno) {
  __shared__ __align__(16) unsigned short Ps[4][16 * 72]; // per-wave [q][tok]
  const int tid = threadIdx.x;
  const int lane = tid & 63, wid = tid >> 6;
  const int li = lane & 15, g = lane >> 4;
  const int bh = blockIdx.y;
  const int q0 = blockIdx.x * 64 + wid * 16;
  const unsigned short* qb = q_ws + (long)bh * 32768;
  const unsigned short* kb = k_ws + (long)bh * 32768;
  const unsigned short* vb = vt_ws + (long)bh * 32768;
  const unsigned short* bias_row = biasb + (long)(q0 + li) * 1024;

  // Q as B-fragment: B[n=li (q)][k=g*8.. (d)]
  bf16x8 qf = *(const bf16x8*)(qb + (q0 + li) * 32 + g * 8);

  // ones B-fragment: B[n=0][k]=1.0 -> col 0 accumulates row sums
  bf16x8 onesf = {};
  if (li == 0) {
#pragma unroll
    for (int j = 0; j < 8; j++) onesf[j] = (short)0x3F80;
  }

  f32x4 o0 = {}, o1 = {}, o2 = {};
  unsigned short* Pw = Ps[wid];

  for (int kv0 = 0; kv0 < 1024; kv0 += 64) {
    // QK^T: A-frags straight from global (coalesced 1KB/instr per wave)
    f32x4 sc[4];
#pragma unroll
    for (int c = 0; c < 4; c++) {
      bf16x8 kf = *(const bf16x8*)(kb + (kv0 + c * 16 + li) * 32 + g * 8);
      uint2 bd = *(const uint2*)(bias_row + kv0 + c * 16 + g * 4);
      f32x4 ci;
      ci[0] = u2f(bd.x << 16);
      ci[1] = u2f(bd.x & 0xffff0000u);
      ci[2] = u2f(bd.y << 16);
      ci[3] = u2f(bd.y & 0xffff0000u);
      sc[c] = __builtin_amdgcn_mfma_f32_16x16x32_bf16(kf, qf, ci, 0, 0, 0);
    }

    // V B-frags from global (16B contiguous rows of Vt) — issue before exp
    // so their latency hides under the softmax VALU work
    bf16x8 vf00 = *(const bf16x8*)(vb + li * 1024 + kv0 + g * 8);
    bf16x8 vf01 = *(const bf16x8*)(vb + (li + 16) * 1024 + kv0 + g * 8);
    bf16x8 vf10 = *(const bf16x8*)(vb + li * 1024 + kv0 + 32 + g * 8);
    bf16x8 vf11 = *(const bf16x8*)(vb + (li + 16) * 1024 + kv0 + 32 + g * 8);

    // p = exp2(sc) (raw v_exp_f32); pack pairs (consecutive toks) -> b64 store
#pragma unroll
    for (int c = 0; c < 4; c++) {
      float p0 = __builtin_amdgcn_exp2f(sc[c][0]);
      float p1 = __builtin_amdgcn_exp2f(sc[c][1]);
      float p2 = __builtin_amdgcn_exp2f(sc[c][2]);
      float p3 = __builtin_amdgcn_exp2f(sc[c][3]);
      unsigned r01, r23;
      asm("v_cvt_pk_bf16_f32 %0, %1, %2" : "=v"(r01) : "v"(p0), "v"(p1));
      asm("v_cvt_pk_bf16_f32 %0, %1, %2" : "=v"(r23) : "v"(p2), "v"(p3));
      uint2 pk; pk.x = r01; pk.y = r23;
      *(uint2*)(Pw + li * 72 + c * 16 + g * 4) = pk;   // toks 16c+4g..+3, q=li
    }

    // PV + ones-column row-sum MFMA (per-wave Ps: in-order DS pipe, no barrier)
    bf16x8 pa0 = *(const bf16x8*)(Pw + li * 72 + g * 8);
    bf16x8 pa1 = *(const bf16x8*)(Pw + li * 72 + 32 + g * 8);
    o0 = __builtin_amdgcn_mfma_f32_16x16x32_bf16(pa0, vf00, o0, 0, 0, 0);
    o1 = __builtin_amdgcn_mfma_f32_16x16x32_bf16(pa0, vf01, o1, 0, 0, 0);
    o2 = __builtin_amdgcn_mfma_f32_16x16x32_bf16(pa0, onesf, o2, 0, 0, 0);
    o0 = __builtin_amdgcn_mfma_f32_16x16x32_bf16(pa1, vf10, o0, 0, 0, 0);
    o1 = __builtin_amdgcn_mfma_f32_16x16x32_bf16(pa1, vf11, o1, 0, 0, 0);
    o2 = __builtin_amdgcn_mfma_f32_16x16x32_bf16(pa1, onesf, o2, 0, 0, 0);
  }

  const int b = bh >> 3, h = bh & 7;
#pragma unroll
  for (int i = 0; i < 4; i++) {
    float s = __shfl(o2[i], lane & 48, 64);  // row sum lives at li==0 lane of this g
    float inv = 1.0f / s;
    int srow = q0 + g * 4 + i;
    long base = ((long)(b * 1024 + srow)) * 256 + h * 32;
    attno[base + li] = f2bf(o0[i] * inv);
    attno[base + 16 + li] = f2bf(o1[i] * inv);
  }
}

// ---------------- launch ----------------
extern "C" void kernel_launch(void* const* d_in, const int* in_sizes, int n_in,
                              void* d_out, int out_size, void* d_ws, size_t ws_size,
                              hipStream_t stream) {
  const float* x      = (const float*)d_in[0];
  const float* wqkv   = (const float*)d_in[1];
  const float* bqkv   = (const float*)d_in[2];
  const float* wmerge = (const float*)d_in[3];
  const float* bmerge = (const float*)d_in[4];
  const float* rtab   = (const float*)d_in[5];
  const int*   ridx   = (const int*)d_in[6];
  float* out = (float*)d_out;

  char* ws = (char*)d_ws;
  unsigned short* xb    = (unsigned short*)(ws);                    //  8 MB
  unsigned short* wqb   = (unsigned short*)(ws + 8388608);          // 384 KB
  unsigned short* wmb   = (unsigned short*)(ws + 8781824);          // 128 KB
  unsigned short* biasb = (unsigned short*)(ws + 8912896);          //  2 MB
  unsigned short* q_ws  = (unsigned short*)(ws + 11010048);         //  8 MB
  unsigned short* k_ws  = (unsigned short*)(ws + 19398656);         //  8 MB
  unsigned short* v_ws  = (unsigned short*)(ws + 27787264);         //  8 MB (transposed [bh][d][s])
  unsigned short* attno = (unsigned short*)(ws + 36175872);         //  8 MB

  prep_kernel<<<5376, 256, 0, stream>>>(x, wqkv, wmerge, rtab, ridx, xb, wqb, wmb, biasb);
  gemm_k<0><<<dim3(6, 128), 256, 0, stream>>>(xb, wqb, bqkv, q_ws, k_ws, v_ws, nullptr);
  attn_kernel<<<dim3(16, 128), 256, 0, stream>>>(q_ws, k_ws, v_ws, biasb, attno);
  gemm_k<1><<<dim3(2, 128), 256, 0, stream>>>(attno, wmb, bmerge, nullptr, nullptr, nullptr, out);
}

// Round 7
// 113.908 us; speedup vs baseline: 1.6509x; 1.6509x over previous
//
#include <hip/hip_runtime.h>

// RelativeMultiHeadSelfAttention: B=16, S=1024, C=256, H=8 heads, D=32 head_dim
// prep (casts + bias gather *INV_LN2) -> QKV GEMM (bf16 MFMA, q scaled by
// SCALE*INV_LN2, V written transposed [bh][d][s]) -> fused attention
// (LDS-staged K/V, R4-verified padded layouts, register PREFETCH pipeline:
// K/V/bias loads for tile t+1 in flight during compute of tile t) -> merge GEMM.

typedef __attribute__((ext_vector_type(8))) short bf16x8;
typedef __attribute__((ext_vector_type(4))) short s16x4;
typedef __attribute__((ext_vector_type(4))) float f32x4;

#define INV_LN2 1.44269504088896340736f

__device__ __forceinline__ unsigned short f2bf(float f) {
  union { float f; unsigned u; } v; v.f = f;
  unsigned r = v.u + 0x7fffu + ((v.u >> 16) & 1u);   // RNE
  return (unsigned short)(r >> 16);
}
__device__ __forceinline__ float u2f(unsigned u) {
  union { unsigned u; float f; } v; v.u = u;
  return v.f;
}

// ---------------- prep: casts + bias gather ----------------
__global__ __launch_bounds__(256) void prep_kernel(
    const float* __restrict__ x, const float* __restrict__ wq,
    const float* __restrict__ wm, const float* __restrict__ tab,
    const int* __restrict__ idx,
    unsigned short* __restrict__ xb, unsigned short* __restrict__ wqb,
    unsigned short* __restrict__ wmb, unsigned short* __restrict__ biasb) {
  const long NX = 1048576, NW1 = 49152, NW2 = 16384, NB = 262144;
  long u = (long)blockIdx.x * 256 + threadIdx.x;
  if (u < NX) {
    float4 v = ((const float4*)x)[u];
    ushort4 o; o.x = f2bf(v.x); o.y = f2bf(v.y); o.z = f2bf(v.z); o.w = f2bf(v.w);
    ((ushort4*)xb)[u] = o;
  } else if (u < NX + NW1) {
    long t = u - NX;
    float4 v = ((const float4*)wq)[t];
    ushort4 o; o.x = f2bf(v.x); o.y = f2bf(v.y); o.z = f2bf(v.z); o.w = f2bf(v.w);
    ((ushort4*)wqb)[t] = o;
  } else if (u < NX + NW1 + NW2) {
    long t = u - NX - NW1;
    float4 v = ((const float4*)wm)[t];
    ushort4 o; o.x = f2bf(v.x); o.y = f2bf(v.y); o.z = f2bf(v.z); o.w = f2bf(v.w);
    ((ushort4*)wmb)[t] = o;
  } else if (u < NX + NW1 + NW2 + NB) {
    long t = u - NX - NW1 - NW2;
    int4 iv = ((const int4*)idx)[t];
    ushort4 o;
    o.x = f2bf(tab[(long)iv.x * 8] * INV_LN2);
    o.y = f2bf(tab[(long)iv.y * 8] * INV_LN2);
    o.z = f2bf(tab[(long)iv.z * 8] * INV_LN2);
    o.w = f2bf(tab[(long)iv.w * 8] * INV_LN2);
    ((ushort4*)biasb)[t] = o;
  }
}

// ---------------- GEMM (QKV / merge) — R3/R4/R5-verified body ----------------
// C[m,n] = sum_k A[m,k]*Bw[n,k] (+ bias[n]); padded LDS [128][40].
// MODE 0: q/k -> [bh][s][32]; V -> TRANSPOSED [bh][d][1024]. MODE 1: f32 out.
template <int MODE>
__global__ __launch_bounds__(256) void gemm_k(
    const unsigned short* __restrict__ A, const unsigned short* __restrict__ Bw,
    const float* __restrict__ bias,
    unsigned short* __restrict__ q_ws, unsigned short* __restrict__ k_ws,
    unsigned short* __restrict__ v_ws, float* __restrict__ out) {
  __shared__ __align__(16) unsigned short As[128 * 40];
  __shared__ __align__(16) unsigned short Bs[128 * 40];
  const int tid = threadIdx.x;
  const int lane = tid & 63, wid = tid >> 6;
  const int wm = wid >> 1, wn = wid & 1;
  const int li = lane & 15, g = lane >> 4;
  const int m0 = blockIdx.y * 128;
  const int n0 = blockIdx.x * 128;
  f32x4 acc[4][4] = {};
  const int srow = tid >> 2, sg = tid & 3;
  const unsigned short* Ag = A + (long)(m0 + srow) * 256 + sg * 8;
  const unsigned short* Bg = Bw + (long)(n0 + srow) * 256 + sg * 8;

  for (int kt = 0; kt < 8; ++kt) {
    const int k0 = kt * 32;
    bf16x8 a0 = *(const bf16x8*)(Ag + k0);
    bf16x8 a1 = *(const bf16x8*)(Ag + 64 * 256 + k0);
    bf16x8 b0 = *(const bf16x8*)(Bg + k0);
    bf16x8 b1 = *(const bf16x8*)(Bg + 64 * 256 + k0);
    __syncthreads();
    *(bf16x8*)(As + srow * 40 + sg * 8) = a0;
    *(bf16x8*)(As + (srow + 64) * 40 + sg * 8) = a1;
    *(bf16x8*)(Bs + srow * 40 + sg * 8) = b0;
    *(bf16x8*)(Bs + (srow + 64) * 40 + sg * 8) = b1;
    __syncthreads();
    bf16x8 af[4], bfr[4];
#pragma unroll
    for (int mi = 0; mi < 4; mi++)
      af[mi] = *(const bf16x8*)(As + (wm * 64 + mi * 16 + li) * 40 + g * 8);
#pragma unroll
    for (int ni = 0; ni < 4; ni++)
      bfr[ni] = *(const bf16x8*)(Bs + (wn * 64 + ni * 16 + li) * 40 + g * 8);
#pragma unroll
    for (int mi = 0; mi < 4; mi++)
#pragma unroll
      for (int ni = 0; ni < 4; ni++)
        acc[mi][ni] = __builtin_amdgcn_mfma_f32_16x16x32_bf16(af[mi], bfr[ni], acc[mi][ni], 0, 0, 0);
  }

  if (MODE == 0) {
    const int sec = n0 >> 8;  // tile never crosses q/k/v section boundaries
    unsigned short* dst = (sec == 0) ? q_ws : k_ws;
    const float qscale = 0.0625f * INV_LN2;   // SCALE * 1/ln2 folded into q
#pragma unroll
    for (int mi = 0; mi < 4; mi++)
#pragma unroll
      for (int ni = 0; ni < 4; ni++)
#pragma unroll
        for (int i = 0; i < 4; i++) {
          int m = m0 + wm * 64 + mi * 16 + g * 4 + i;
          int n = n0 + wn * 64 + ni * 16 + li;
          float val = acc[mi][ni][i] + bias[n];
          if (sec == 0) val *= qscale;
          int h = (n >> 5) & 7, d = n & 31;
          int b = m >> 10, s = m & 1023;
          if (sec == 2)
            v_ws[(long)(b * 8 + h) * 32768 + (long)d * 1024 + s] = f2bf(val);
          else
            dst[((long)(b * 8 + h) * 1024 + s) * 32 + d] = f2bf(val);
        }
  } else {
#pragma unroll
    for (int mi = 0; mi < 4; mi++)
#pragma unroll
      for (int ni = 0; ni < 4; ni++)
#pragma unroll
        for (int i = 0; i < 4; i++) {
          int m = m0 + wm * 64 + mi * 16 + g * 4 + i;
          int n = n0 + wn * 64 + ni * 16 + li;
          out[(long)m * 256 + n] = acc[mi][ni][i] + bias[n];
        }
  }
}

// ---------------- fused attention (prefetch pipeline, R4-verified layouts) --
// grid (16 q-tiles, 128 bh); 4 waves/WG, each owns 16 q rows.
// sc = mfma(A=K, B=Q, C=bias_l2): lane (li,g) reg i = P[tok=16c+4g+i][q=li].
// K/V/bias for tile t+1 prefetched into regs during compute of tile t.
__global__ __launch_bounds__(256) void attn_kernel(
    const unsigned short* __restrict__ q_ws, const unsigned short* __restrict__ k_ws,
    const unsigned short* __restrict__ vt_ws, const unsigned short* __restrict__ biasb,
    unsigned short* __restrict__ attno) {
  __shared__ __align__(16) unsigned short Ks[64 * 40];    // [tok][d] pad40
  __shared__ __align__(16) unsigned short Vt[32 * 72];    // [d][tok] pad72
  __shared__ __align__(16) unsigned short Ps[4][16 * 72]; // per-wave [q][tok] pad72
  const int tid = threadIdx.x;
  const int lane = tid & 63, wid = tid >> 6;
  const int li = lane & 15, g = lane >> 4;
  const int bh = blockIdx.y;
  const int q0 = blockIdx.x * 64 + wid * 16;
  const unsigned short* qb = q_ws + (long)bh * 32768;
  const unsigned short* kb = k_ws + (long)bh * 32768;
  const unsigned short* vb = vt_ws + (long)bh * 32768;
  const unsigned short* bias_row = biasb + (long)(q0 + li) * 1024;

  // Q as B-fragment: B[n=li (q)][k=g*8.. (d)]
  bf16x8 qf = *(const bf16x8*)(qb + (q0 + li) * 32 + g * 8);

  // ones B-fragment: B[n=0][k]=1.0 -> col 0 accumulates row sums
  bf16x8 onesf = {};
  if (li == 0) {
#pragma unroll
    for (int j = 0; j < 8; j++) onesf[j] = (short)0x3F80;
  }

  f32x4 o0 = {}, o1 = {}, o2 = {};
  unsigned short* Pw = Ps[wid];

  // staging geometry
  const int kt_r = tid >> 2, kt_c = (tid & 3) * 8;   // K: tok row, d-chunk
  const int vd_r = tid >> 3, vd_c = (tid & 7) * 8;   // V: d row, tok-chunk

  // prologue: prefetch tile 0 (K, V, bias) into regs
  bf16x8 kst = *(const bf16x8*)(kb + kt_r * 32 + kt_c);
  bf16x8 vst = *(const bf16x8*)(vb + vd_r * 1024 + vd_c);
  uint2 bnx[4];
#pragma unroll
  for (int c = 0; c < 4; c++)
    bnx[c] = *(const uint2*)(bias_row + c * 16 + g * 4);

  for (int kv0 = 0; kv0 < 1024; kv0 += 64) {
    __syncthreads();                       // prev iteration's LDS reads done
    *(bf16x8*)(Ks + kt_r * 40 + kt_c) = kst;
    *(bf16x8*)(Vt + vd_r * 72 + vd_c) = vst;
    // prefetch tile t+1 (last-iter OOB reads land in allocated ws, unused)
    kst = *(const bf16x8*)(kb + (kv0 + 64 + kt_r) * 32 + kt_c);
    vst = *(const bf16x8*)(vb + vd_r * 1024 + kv0 + 64 + vd_c);
    uint2 bcur[4];
#pragma unroll
    for (int c = 0; c < 4; c++) {
      bcur[c] = bnx[c];
      bnx[c] = *(const uint2*)(bias_row + kv0 + 64 + c * 16 + g * 4);
    }
    __syncthreads();                       // LDS ready

    // swapped QK^T: sc[c] = mfma(A=K, B=Q, C=bias_l2 from regs)
    f32x4 sc[4];
#pragma unroll
    for (int c = 0; c < 4; c++) {
      bf16x8 kf = *(const bf16x8*)(Ks + (c * 16 + li) * 40 + g * 8);
      f32x4 ci;
      ci[0] = u2f(bcur[c].x << 16);
      ci[1] = u2f(bcur[c].x & 0xffff0000u);
      ci[2] = u2f(bcur[c].y << 16);
      ci[3] = u2f(bcur[c].y & 0xffff0000u);
      sc[c] = __builtin_amdgcn_mfma_f32_16x16x32_bf16(kf, qf, ci, 0, 0, 0);
    }

    // p = exp2(sc); pack tok-pairs; b64 store into Ps[q][tok] (R4 addressing)
#pragma unroll
    for (int c = 0; c < 4; c++) {
      float p0 = __builtin_amdgcn_exp2f(sc[c][0]);
      float p1 = __builtin_amdgcn_exp2f(sc[c][1]);
      float p2 = __builtin_amdgcn_exp2f(sc[c][2]);
      float p3 = __builtin_amdgcn_exp2f(sc[c][3]);
      unsigned r01, r23;
      asm("v_cvt_pk_bf16_f32 %0, %1, %2" : "=v"(r01) : "v"(p0), "v"(p1));
      asm("v_cvt_pk_bf16_f32 %0, %1, %2" : "=v"(r23) : "v"(p2), "v"(p3));
      union { uint2 u; s16x4 s; } pw;
      pw.u.x = r01; pw.u.y = r23;
      *(s16x4*)(Pw + li * 72 + c * 16 + g * 4) = pw.s;   // toks 16c+4g..+3, q=li
    }
    __builtin_amdgcn_sched_barrier(0);     // keep P-stores before P-reads

    // PV + ones-column row-sum MFMA (per-wave Ps: no barrier needed)
#pragma unroll
    for (int c2 = 0; c2 < 2; c2++) {
      bf16x8 pa  = *(const bf16x8*)(Pw + li * 72 + c2 * 32 + g * 8);
      bf16x8 vf0 = *(const bf16x8*)(Vt + li * 72 + c2 * 32 + g * 8);
      bf16x8 vf1 = *(const bf16x8*)(Vt + (li + 16) * 72 + c2 * 32 + g * 8);
      o0 = __builtin_amdgcn_mfma_f32_16x16x32_bf16(pa, vf0, o0, 0, 0, 0);
      o1 = __builtin_amdgcn_mfma_f32_16x16x32_bf16(pa, vf1, o1, 0, 0, 0);
      o2 = __builtin_amdgcn_mfma_f32_16x16x32_bf16(pa, onesf, o2, 0, 0, 0);
    }
  }

  const int b = bh >> 3, h = bh & 7;
#pragma unroll
  for (int i = 0; i < 4; i++) {
    float s = __shfl(o2[i], lane & 48, 64);  // row sum lives at li==0 lane of this g
    float inv = 1.0f / s;
    int srow = q0 + g * 4 + i;
    long base = ((long)(b * 1024 + srow)) * 256 + h * 32;
    attno[base + li] = f2bf(o0[i] * inv);
    attno[base + 16 + li] = f2bf(o1[i] * inv);
  }
}

// ---------------- launch ----------------
extern "C" void kernel_launch(void* const* d_in, const int* in_sizes, int n_in,
                              void* d_out, int out_size, void* d_ws, size_t ws_size,
                              hipStream_t stream) {
  const float* x      = (const float*)d_in[0];
  const float* wqkv   = (const float*)d_in[1];
  const float* bqkv   = (const float*)d_in[2];
  const float* wmerge = (const float*)d_in[3];
  const float* bmerge = (const float*)d_in[4];
  const float* rtab   = (const float*)d_in[5];
  const int*   ridx   = (const int*)d_in[6];
  float* out = (float*)d_out;

  char* ws = (char*)d_ws;
  unsigned short* xb    = (unsigned short*)(ws);                    //  8 MB
  unsigned short* wqb   = (unsigned short*)(ws + 8388608);          // 384 KB
  unsigned short* wmb   = (unsigned short*)(ws + 8781824);          // 128 KB
  unsigned short* biasb = (unsigned short*)(ws + 8912896);          //  2 MB
  unsigned short* q_ws  = (unsigned short*)(ws + 11010048);         //  8 MB
  unsigned short* k_ws  = (unsigned short*)(ws + 19398656);         //  8 MB
  unsigned short* v_ws  = (unsigned short*)(ws + 27787264);         //  8 MB (transposed [bh][d][s])
  unsigned short* attno = (unsigned short*)(ws + 36175872);         //  8 MB

  prep_kernel<<<5376, 256, 0, stream>>>(x, wqkv, wmerge, rtab, ridx, xb, wqb, wmb, biasb);
  gemm_k<0><<<dim3(6, 128), 256, 0, stream>>>(xb, wqb, bqkv, q_ws, k_ws, v_ws, nullptr);
  attn_kernel<<<dim3(16, 128), 256, 0, stream>>>(q_ws, k_ws, v_ws, biasb, attno);
  gemm_k<1><<<dim3(2, 128), 256, 0, stream>>>(attno, wmb, bmerge, nullptr, nullptr, nullptr, out);
}